// Round 8
// baseline (84.330 us; speedup 1.0000x reference)
//
#include <hip/hip_runtime.h>

// BilateralFilter fp32, 8 images 512x512, 3x3, sigma=0.8.
// v8 = R5's pair-symmetric 2x4 tile, restructured for 4 blocks/CU residency:
//  - __launch_bounds__(256,4): cap 128 VGPR so all 4 blocks/CU are resident
//    (grid is exactly 4 blocks/CU; VGPR>128 would serialize a tail block).
//  - center-tap folded into accumulator INIT inside HPASS (kills the 32-reg
//    center-save of R5/R6); windows streamed T->A->B->T2, peak ~120 live.
//  - aligned x2/x4/x2 full-wave loads with precomputed clamped col offsets
//    (no per-lane exec-masked scalar edge loads).

constexpr int HH = 512, WW = 512, HW = HH * WW;

#define KEXP (-1.1271055f)             // -(1/(2*0.8^2)) * log2(e)
#define E2(x) __builtin_amdgcn_exp2f(x)
#define WS0f 0.2724967f                // normalized spatial gaussian, d2=0
#define WS1f 0.1247577f                // d2=1
#define WS2f 0.0571180f                // d2=2

__global__ __launch_bounds__(256, 4) void bilateral_v8(
    const float* __restrict__ depth,   // [N,1,H,W]
    const float* __restrict__ color,   // [N,3,H,W]
    const float* __restrict__ mask,    // [N,1,H,W]
    float* __restrict__ out)           // [N,3,H,W]
{
    const int lane = threadIdx.x & 63;
    const int wg   = blockIdx.x * 4 + (threadIdx.x >> 6);
    const int n    = wg >> 9;               // image 0..7
    const int rem  = wg & 511;
    const int hp   = rem >> 1;              // row-pair 0..255
    const int half = rem & 1;               // column half
    const int rA   = hp * 2;
    const int c0   = half * 256 + lane * 4;

    const float* dptr = depth + (size_t)n * HW;
    const float* mptr = mask  + (size_t)n * HW;
    const float* xptr = color + (size_t)n * 3 * HW;
    const float* yptr = xptr + HW;
    const float* zptr = xptr + 2 * HW;

    const bool hasL = (c0 > 0);
    const bool hasR = (c0 < WW - 4);
    const int  colL = hasL ? c0 - 2 : c0;   // aligned dwordx2; clamped lane
    const int  colR = hasR ? c0 + 4 : c0;   // aligned dwordx2; clamped lane

    // Window rows: cols 0..5 = w-1..w+4.
    float TD[6], TM[6], TX[6], TY[6], TZ[6];   // side row (rA-1, then rA+2)
    float AD[6], AM[6], AX[6], AY[6], AZ[6];   // row rA
    float BD[6], BM[6], BX[6], BY[6], BZ[6];   // row rA+1

#define LOADP(W, base, off) do {                                             \
    const float4 _m = *reinterpret_cast<const float4*>((base) + (off) + c0); \
    const float2 _l = *reinterpret_cast<const float2*>((base) + (off) + colL); \
    const float2 _r = *reinterpret_cast<const float2*>((base) + (off) + colR); \
    W[1] = _m.x; W[2] = _m.y; W[3] = _m.z; W[4] = _m.w;                      \
    W[0] = hasL ? _l.y : 0.0f;                                               \
    W[5] = hasR ? _r.x : 0.0f;                                               \
} while (0)

#define LOADW(D_, M_, X_, Y_, Z_, r) do {                                    \
    const int _off = (r) * WW;                                               \
    LOADP(D_, dptr, _off); LOADP(M_, mptr, _off);                            \
    LOADP(X_, xptr, _off); LOADP(Y_, yptr, _off); LOADP(Z_, zptr, _off);     \
} while (0)

    float aSwd[4], aSwc[4], aSt[4], aS0[4], aS1[4], aS2[4];
    float bSwd[4], bSwc[4], bSt[4], bS0[4], bS1[4], bS2[4];

// Horizontal pass: INITIALIZES accumulators (center tap + E/W shared pairs).
#define HPASS(D_, M_, X_, Y_, Z_, Swd, Swc, St, S0, S1, S2) do {             \
    float hwd[5], hwc[5];                                                    \
    _Pragma("unroll") for (int j = 0; j < 5; ++j) {                          \
        const float dd = D_[j] - D_[j + 1];                                  \
        hwd[j] = E2(KEXP * dd * dd);                                         \
        const float f0 = X_[j] - X_[j + 1];                                  \
        const float f1 = Y_[j] - Y_[j + 1];                                  \
        const float f2 = Z_[j] - Z_[j + 1];                                  \
        hwc[j] = E2(KEXP * f0 * f0) + E2(KEXP * f1 * f1)                     \
               + E2(KEXP * f2 * f2);                                         \
    }                                                                        \
    _Pragma("unroll") for (int i = 0; i < 4; ++i) {                          \
        const int ci = i + 1;                                                \
        const float tc = (3.0f * WS0f) * M_[ci];                             \
        const float tw = hwd[i]   * hwc[i]   * WS1f * M_[i];                 \
        const float te = hwd[i+1] * hwc[i+1] * WS1f * M_[i+2];               \
        Swd[i] = 1.0f + hwd[i] + hwd[i+1];                                   \
        Swc[i] = 3.0f + hwc[i] + hwc[i+1];                                   \
        St[i]  = tc + tw + te;                                               \
        S0[i]  = tc * X_[ci] + tw * X_[i] + te * X_[i+2];                    \
        S1[i]  = tc * Y_[ci] + tw * Y_[i] + te * Y_[i+2];                    \
        S2[i]  = tc * Z_[ci] + tw * Z_[i] + te * Z_[i+2];                    \
    }                                                                        \
} while (0)

// One-sided pass: side-row window T vs centers from intact row window R.
#define SIDE(D_, M_, X_, Y_, Z_, RD, RX, RY, RZ, Swd, Swc, St, S0, S1, S2) do { \
    _Pragma("unroll") for (int i = 0; i < 4; ++i) {                          \
        const float cd = RD[i + 1];                                          \
        const float cx = RX[i + 1];                                          \
        const float cy = RY[i + 1];                                          \
        const float cz = RZ[i + 1];                                          \
        _Pragma("unroll") for (int dj = 0; dj < 3; ++dj) {                   \
            const int c = i + dj;                                            \
            const float dd = D_[c] - cd;                                     \
            const float wd = E2(KEXP * dd * dd);                             \
            const float f0 = X_[c] - cx;                                     \
            const float f1 = Y_[c] - cy;                                     \
            const float f2 = Z_[c] - cz;                                     \
            const float wc = E2(KEXP * f0 * f0) + E2(KEXP * f1 * f1)         \
                           + E2(KEXP * f2 * f2);                             \
            const float ws = (dj == 1) ? WS1f : WS2f;                        \
            const float t = wd * wc * ws * M_[c];                            \
            Swd[i] += wd; Swc[i] += wc; St[i] += t;                          \
            S0[i] += t * X_[c]; S1[i] += t * Y_[c]; S2[i] += t * Z_[c];      \
        }                                                                    \
    }                                                                        \
} while (0)

    const bool hasUp = (hp > 0);      // wave-uniform
    const bool hasDn = (hp < 255);    // wave-uniform

    // Issue all three row windows up-front (MLP).
    if (hasUp) LOADW(TD, TM, TX, TY, TZ, rA - 1);
    LOADW(AD, AM, AX, AY, AZ, rA);
    LOADW(BD, BM, BX, BY, BZ, rA + 1);

    HPASS(AD, AM, AX, AY, AZ, aSwd, aSwc, aSt, aS0, aS1, aS2);   // init a
    if (hasUp)
        SIDE(TD, TM, TX, TY, TZ, AD, AX, AY, AZ,
             aSwd, aSwc, aSt, aS0, aS1, aS2);
    HPASS(BD, BM, BX, BY, BZ, bSwd, bSwc, bSt, bS0, bS1, bS2);   // init b

    // Vertical + diagonal pairs between rows A and B (computed once,
    // accumulated into both interior endpoints). A dies after this.
    #pragma unroll
    for (int a = 0; a < 6; ++a) {
        #pragma unroll
        for (int db = -1; db <= 1; ++db) {
            const int bb = a + db;
            if (bb < 0 || bb > 5) continue;
            const bool useA = (a >= 1 && a <= 4);
            const bool useB = (bb >= 1 && bb <= 4);
            if (!useA && !useB) continue;
            const float dd = AD[a] - BD[bb];
            const float pwd = E2(KEXP * dd * dd);
            const float f0 = AX[a] - BX[bb];
            const float f1 = AY[a] - BY[bb];
            const float f2 = AZ[a] - BZ[bb];
            const float pwc = E2(KEXP * f0 * f0) + E2(KEXP * f1 * f1)
                            + E2(KEXP * f2 * f2);
            const float g = pwd * pwc;
            const float ws = (db == 0) ? WS1f : WS2f;
            if (useA) {
                const int i = a - 1;
                const float t = g * ws * BM[bb];
                aSwd[i] += pwd; aSwc[i] += pwc; aSt[i] += t;
                aS0[i] += t * BX[bb]; aS1[i] += t * BY[bb]; aS2[i] += t * BZ[bb];
            }
            if (useB) {
                const int i = bb - 1;
                const float t = g * ws * AM[a];
                bSwd[i] += pwd; bSwc[i] += pwc; bSt[i] += t;
                bS0[i] += t * AX[a]; bS1[i] += t * AY[a]; bS2[i] += t * AZ[a];
            }
        }
    }

    // Bottom side row into T's registers; SIDE-down vs intact B.
    if (hasDn) {
        LOADW(TD, TM, TX, TY, TZ, rA + 2);
        SIDE(TD, TM, TX, TY, TZ, BD, BX, BY, BZ,
             bSwd, bSwc, bSt, bS0, bS1, bS2);
    }
    // (skipped side passes at image top/bottom only omit the zero-pad rows'
    //  contribution to the 9e-7 guard term -> error << 1e-3)

    // out = Stc / (St + 9e-7 * Swd * Swc)
    float oa0[4], oa1[4], oa2[4], ob0[4], ob1[4], ob2[4];
    #pragma unroll
    for (int i = 0; i < 4; ++i) {
        const float invA = __builtin_amdgcn_rcpf(aSt[i] + 9e-7f * aSwd[i] * aSwc[i]);
        oa0[i] = aS0[i] * invA; oa1[i] = aS1[i] * invA; oa2[i] = aS2[i] * invA;
        const float invB = __builtin_amdgcn_rcpf(bSt[i] + 9e-7f * bSwd[i] * bSwc[i]);
        ob0[i] = bS0[i] * invB; ob1[i] = bS1[i] * invB; ob2[i] = bS2[i] * invB;
    }

    float* po = out + (size_t)n * 3 * HW + rA * WW + c0;
    *reinterpret_cast<float4*>(po)               = make_float4(oa0[0], oa0[1], oa0[2], oa0[3]);
    *reinterpret_cast<float4*>(po + HW)          = make_float4(oa1[0], oa1[1], oa1[2], oa1[3]);
    *reinterpret_cast<float4*>(po + 2 * HW)      = make_float4(oa2[0], oa2[1], oa2[2], oa2[3]);
    *reinterpret_cast<float4*>(po + WW)          = make_float4(ob0[0], ob0[1], ob0[2], ob0[3]);
    *reinterpret_cast<float4*>(po + WW + HW)     = make_float4(ob1[0], ob1[1], ob1[2], ob1[3]);
    *reinterpret_cast<float4*>(po + WW + 2 * HW) = make_float4(ob2[0], ob2[1], ob2[2], ob2[3]);
}

extern "C" void kernel_launch(void* const* d_in, const int* in_sizes, int n_in,
                              void* d_out, int out_size, void* d_ws, size_t ws_size,
                              hipStream_t stream) {
    const float* depth = (const float*)d_in[0];
    const float* color = (const float*)d_in[1];
    const float* mask  = (const float*)d_in[2];
    float* out = (float*)d_out;

    // 8 images * 256 row-pairs * 2 halves = 4096 waves; 4 waves/block
    bilateral_v8<<<1024, 256, 0, stream>>>(depth, color, mask, out);
}

// Round 9
// 26.053 us; speedup vs baseline: 3.2368x; 3.2368x over previous
//
#include <hip/hip_runtime.h>

// BilateralFilter fp32, 8 images 512x512, 3x3, sigma=0.8.
// v9 = R5 pair-symmetric 2x4 core, register-dieted for 4 waves/SIMD:
//  - __launch_bounds__(256,2): empirically caps VGPR at ~128 on this
//    toolchain (3->84, 4->64 observed; 2->128). Live set kept ~120:
//    never 3 windows at once. A+B windows -> HPASS/GAP -> reduce to
//    16-float center sets -> stream side rows through freed regs.
//  - R8's aligned x4+x2 clamped loads (no per-lane exec-masked gathers).

constexpr int HH = 512, WW = 512, HW = HH * WW;

#define KEXP (-1.1271055f)             // -(1/(2*0.8^2)) * log2(e)
#define E2(x) __builtin_amdgcn_exp2f(x)
#define WS0f 0.2724967f                // normalized spatial gaussian, d2=0
#define WS1f 0.1247577f                // d2=1
#define WS2f 0.0571180f                // d2=2

__global__ __launch_bounds__(256, 2) void bilateral_v9(
    const float* __restrict__ depth,   // [N,1,H,W]
    const float* __restrict__ color,   // [N,3,H,W]
    const float* __restrict__ mask,    // [N,1,H,W]
    float* __restrict__ out)           // [N,3,H,W]
{
    const int lane = threadIdx.x & 63;
    const int wg   = blockIdx.x * 4 + (threadIdx.x >> 6);
    const int n    = wg >> 9;               // image 0..7
    const int rem  = wg & 511;
    const int hp   = rem >> 1;              // row-pair 0..255
    const int half = rem & 1;               // column half
    const int rA   = hp * 2;
    const int c0   = half * 256 + lane * 4;

    const float* dptr = depth + (size_t)n * HW;
    const float* mptr = mask  + (size_t)n * HW;
    const float* xptr = color + (size_t)n * 3 * HW;
    const float* yptr = xptr + HW;
    const float* zptr = xptr + 2 * HW;

    const bool hasL = (c0 > 0);
    const bool hasR = (c0 < WW - 4);
    const int  colL = hasL ? c0 - 2 : c0;   // aligned dwordx2, clamped
    const int  colR = hasR ? c0 + 4 : c0;   // aligned dwordx2, clamped

    // Two window sets only. Cols 0..5 = w-1..w+4.
    float UD[6], UM[6], UX[6], UY[6], UZ[6];   // row rA, later side row rA-1
    float VD[6], VM[6], VX[6], VY[6], VZ[6];   // row rA+1, later side row rA+2

#define LOADP(W, base, off) do {                                             \
    const float4 _m = *reinterpret_cast<const float4*>((base) + (off) + c0); \
    const float2 _l = *reinterpret_cast<const float2*>((base) + (off) + colL); \
    const float2 _r = *reinterpret_cast<const float2*>((base) + (off) + colR); \
    W[1] = _m.x; W[2] = _m.y; W[3] = _m.z; W[4] = _m.w;                      \
    W[0] = hasL ? _l.y : 0.0f;                                               \
    W[5] = hasR ? _r.x : 0.0f;                                               \
} while (0)

#define LOADW(D_, M_, X_, Y_, Z_, r) do {                                    \
    const int _off = (r) * WW;                                               \
    LOADP(D_, dptr, _off); LOADP(M_, mptr, _off);                            \
    LOADP(X_, xptr, _off); LOADP(Y_, yptr, _off); LOADP(Z_, zptr, _off);     \
} while (0)

    float aSwd[4], aSwc[4], aSt[4], aS0[4], aS1[4], aS2[4];
    float bSwd[4], bSwc[4], bSt[4], bS0[4], bS1[4], bS2[4];

// Horizontal pass: INITIALIZES accumulators (center tap + shared E/W pairs).
#define HPASS(D_, M_, X_, Y_, Z_, Swd, Swc, St, S0, S1, S2) do {             \
    float hwd[5], hwc[5];                                                    \
    _Pragma("unroll") for (int j = 0; j < 5; ++j) {                          \
        const float dd = D_[j] - D_[j + 1];                                  \
        hwd[j] = E2(KEXP * dd * dd);                                         \
        const float f0 = X_[j] - X_[j + 1];                                  \
        const float f1 = Y_[j] - Y_[j + 1];                                  \
        const float f2 = Z_[j] - Z_[j + 1];                                  \
        hwc[j] = E2(KEXP * f0 * f0) + E2(KEXP * f1 * f1)                     \
               + E2(KEXP * f2 * f2);                                         \
    }                                                                        \
    _Pragma("unroll") for (int i = 0; i < 4; ++i) {                          \
        const int ci = i + 1;                                                \
        const float tc = (3.0f * WS0f) * M_[ci];                             \
        const float tw = hwd[i]   * hwc[i]   * WS1f * M_[i];                 \
        const float te = hwd[i+1] * hwc[i+1] * WS1f * M_[i+2];               \
        Swd[i] = 1.0f + hwd[i] + hwd[i+1];                                   \
        Swc[i] = 3.0f + hwc[i] + hwc[i+1];                                   \
        St[i]  = tc + tw + te;                                               \
        S0[i]  = tc * X_[ci] + tw * X_[i] + te * X_[i+2];                    \
        S1[i]  = tc * Y_[ci] + tw * Y_[i] + te * Y_[i+2];                    \
        S2[i]  = tc * Z_[ci] + tw * Z_[i] + te * Z_[i+2];                    \
    }                                                                        \
} while (0)

// One-sided pass: side-row window vs saved 16-float center set.
#define SIDE(D_, M_, X_, Y_, Z_, cd_, cx_, cy_, cz_, Swd, Swc, St, S0, S1, S2) do { \
    _Pragma("unroll") for (int i = 0; i < 4; ++i) {                          \
        const float cd = cd_[i];                                             \
        const float cx = cx_[i];                                             \
        const float cy = cy_[i];                                             \
        const float cz = cz_[i];                                             \
        _Pragma("unroll") for (int dj = 0; dj < 3; ++dj) {                   \
            const int c = i + dj;                                            \
            const float dd = D_[c] - cd;                                     \
            const float wd = E2(KEXP * dd * dd);                             \
            const float f0 = X_[c] - cx;                                     \
            const float f1 = Y_[c] - cy;                                     \
            const float f2 = Z_[c] - cz;                                     \
            const float wc = E2(KEXP * f0 * f0) + E2(KEXP * f1 * f1)         \
                           + E2(KEXP * f2 * f2);                             \
            const float ws = (dj == 1) ? WS1f : WS2f;                        \
            const float t = wd * wc * ws * M_[c];                            \
            Swd[i] += wd; Swc[i] += wc; St[i] += t;                          \
            S0[i] += t * X_[c]; S1[i] += t * Y_[c]; S2[i] += t * Z_[c];      \
        }                                                                    \
    }                                                                        \
} while (0)

    const bool hasUp = (hp > 0);      // wave-uniform
    const bool hasDn = (hp < 255);    // wave-uniform

    // Issue both center-row windows up-front (30 VMEM in flight).
    LOADW(UD, UM, UX, UY, UZ, rA);
    LOADW(VD, VM, VX, VY, VZ, rA + 1);

    HPASS(UD, UM, UX, UY, UZ, aSwd, aSwc, aSt, aS0, aS1, aS2);   // init a
    HPASS(VD, VM, VX, VY, VZ, bSwd, bSwc, bSt, bS0, bS1, bS2);   // init b

    // Vertical + diagonal pairs between rows rA and rA+1 (computed once,
    // accumulated into both interior endpoints). Peak-live region.
    #pragma unroll
    for (int a = 0; a < 6; ++a) {
        #pragma unroll
        for (int db = -1; db <= 1; ++db) {
            const int bb = a + db;
            if (bb < 0 || bb > 5) continue;
            const bool useA = (a >= 1 && a <= 4);
            const bool useB = (bb >= 1 && bb <= 4);
            if (!useA && !useB) continue;
            const float dd = UD[a] - VD[bb];
            const float pwd = E2(KEXP * dd * dd);
            const float f0 = UX[a] - VX[bb];
            const float f1 = UY[a] - VY[bb];
            const float f2 = UZ[a] - VZ[bb];
            const float pwc = E2(KEXP * f0 * f0) + E2(KEXP * f1 * f1)
                            + E2(KEXP * f2 * f2);
            const float g = pwd * pwc;
            const float ws = (db == 0) ? WS1f : WS2f;
            if (useA) {
                const int i = a - 1;
                const float t = g * ws * VM[bb];
                aSwd[i] += pwd; aSwc[i] += pwc; aSt[i] += t;
                aS0[i] += t * VX[bb]; aS1[i] += t * VY[bb]; aS2[i] += t * VZ[bb];
            }
            if (useB) {
                const int i = bb - 1;
                const float t = g * ws * UM[a];
                bSwd[i] += pwd; bSwc[i] += pwc; bSt[i] += t;
                bS0[i] += t * UX[a]; bS1[i] += t * UY[a]; bS2[i] += t * UZ[a];
            }
        }
    }

    // Reduce both windows to their 16-float center sets; windows die here.
    float cdA[4], cxA[4], cyA[4], czA[4];
    float cdB[4], cxB[4], cyB[4], czB[4];
    #pragma unroll
    for (int i = 0; i < 4; ++i) {
        cdA[i] = UD[i+1]; cxA[i] = UX[i+1]; cyA[i] = UY[i+1]; czA[i] = UZ[i+1];
        cdB[i] = VD[i+1]; cxB[i] = VX[i+1]; cyB[i] = VY[i+1]; czB[i] = VZ[i+1];
    }

    // Side row rA-1 streams through U's registers.
    if (hasUp) {
        LOADW(UD, UM, UX, UY, UZ, rA - 1);
        SIDE(UD, UM, UX, UY, UZ, cdA, cxA, cyA, czA,
             aSwd, aSwc, aSt, aS0, aS1, aS2);
    }
    // Side row rA+2 streams through V's registers.
    if (hasDn) {
        LOADW(VD, VM, VX, VY, VZ, rA + 2);
        SIDE(VD, VM, VX, VY, VZ, cdB, cxB, cyB, czB,
             bSwd, bSwc, bSt, bS0, bS1, bS2);
    }
    // (skipped side passes at image top/bottom only omit the zero-pad rows'
    //  contribution to the 9e-7 guard term -> error << 1e-3)

    // out = Stc / (St + 9e-7 * Swd * Swc)
    float oa0[4], oa1[4], oa2[4], ob0[4], ob1[4], ob2[4];
    #pragma unroll
    for (int i = 0; i < 4; ++i) {
        const float invA = __builtin_amdgcn_rcpf(aSt[i] + 9e-7f * aSwd[i] * aSwc[i]);
        oa0[i] = aS0[i] * invA; oa1[i] = aS1[i] * invA; oa2[i] = aS2[i] * invA;
        const float invB = __builtin_amdgcn_rcpf(bSt[i] + 9e-7f * bSwd[i] * bSwc[i]);
        ob0[i] = bS0[i] * invB; ob1[i] = bS1[i] * invB; ob2[i] = bS2[i] * invB;
    }

    float* po = out + (size_t)n * 3 * HW + rA * WW + c0;
    *reinterpret_cast<float4*>(po)               = make_float4(oa0[0], oa0[1], oa0[2], oa0[3]);
    *reinterpret_cast<float4*>(po + HW)          = make_float4(oa1[0], oa1[1], oa1[2], oa1[3]);
    *reinterpret_cast<float4*>(po + 2 * HW)      = make_float4(oa2[0], oa2[1], oa2[2], oa2[3]);
    *reinterpret_cast<float4*>(po + WW)          = make_float4(ob0[0], ob0[1], ob0[2], ob0[3]);
    *reinterpret_cast<float4*>(po + WW + HW)     = make_float4(ob1[0], ob1[1], ob1[2], ob1[3]);
    *reinterpret_cast<float4*>(po + WW + 2 * HW) = make_float4(ob2[0], ob2[1], ob2[2], ob2[3]);
}

extern "C" void kernel_launch(void* const* d_in, const int* in_sizes, int n_in,
                              void* d_out, int out_size, void* d_ws, size_t ws_size,
                              hipStream_t stream) {
    const float* depth = (const float*)d_in[0];
    const float* color = (const float*)d_in[1];
    const float* mask  = (const float*)d_in[2];
    float* out = (float*)d_out;

    // 8 images * 256 row-pairs * 2 halves = 4096 waves; 4 waves/block
    bilateral_v9<<<1024, 256, 0, stream>>>(depth, color, mask, out);
}

// Round 11
// 24.143 us; speedup vs baseline: 3.4929x; 1.0791x over previous
//
#include <hip/hip_runtime.h>

// BilateralFilter fp32 I/O, 8 images 512x512, 3x3, sigma=0.8.
// v11 = v10 with the cvt_pkrtz type fixed (bit_cast to _Float16x2).
// Packed-fp16 compute (2 px per v_pk_* instruction), weight exp replaced by
// degree-4 polynomial of s = diff^2 (w = e^(-0.78125*s), s in [0,1]).
// Zero transcendentals. 2 rows x 4 cols/thread, fp16 accum, fp32 epilogue.

typedef _Float16 h2 __attribute__((ext_vector_type(2)));

constexpr int HH = 512, WW = 512, HW = HH * WW;

__device__ __forceinline__ h2 H2c(float v) { return h2{(_Float16)v, (_Float16)v}; }

__device__ __forceinline__ h2 pkrtz(float a, float b) {
    return __builtin_bit_cast(h2, __builtin_amdgcn_cvt_pkrtz(a, b));
}

// w(s) = e^(-0.78125*s) = e^(-0.78125*(v+0.5)), v = s-0.5 in [-0.5,0.5].
// Degree-4 Taylor at s=0.5: b0=0.676634 b1=-0.528620 b2=0.206495
// b3=-0.0537742 b4=0.0105029 (rel err ~5e-5).
__device__ __forceinline__ h2 wpoly(h2 d) {
    h2 v = d * d + H2c(-0.5f);                      // v = s - 0.5 (pk_fma)
    h2 w = H2c(-0.0537742f) + v * H2c(0.0105029f);
    w = H2c(0.206495f) + v * w;
    w = H2c(-0.528620f) + v * w;
    w = H2c(0.676634f) + v * w;
    return w;
}

// Spatial gaussian (normalized): d2=0,1,2
#define WS0f 0.2724967f
#define WS1f 0.1247577f
#define WS2f 0.0571180f

struct RW {              // one row window, 5 planes x 5 packs, 25 VGPR
    // pack idx: 0=(c0,c1) 1=(c1,c2) 2=(c2,c3) 3=(c3,c4) 4=(c4,c5)
    h2 d[5], m[5], x[5], y[5], z[5];
};
struct Acc { h2 swd, swc, st, s0, s1, s2; };

__global__ __launch_bounds__(256) void bilateral_v11(
    const float* __restrict__ depth,
    const float* __restrict__ color,
    const float* __restrict__ mask,
    float* __restrict__ out)
{
    const int lane = threadIdx.x & 63;
    const int wg   = blockIdx.x * 4 + (threadIdx.x >> 6);
    const int n    = wg >> 9;
    const int rem  = wg & 511;
    const int hp   = rem >> 1;              // row-pair 0..255
    const int half = rem & 1;
    const int rA   = hp * 2;
    const int c0   = half * 256 + lane * 4;

    const float* dptr = depth + (size_t)n * HW;
    const float* mptr = mask  + (size_t)n * HW;
    const float* xptr = color + (size_t)n * 3 * HW;
    const float* yptr = xptr + HW;
    const float* zptr = xptr + 2 * HW;

    const bool hasL = (c0 > 0);
    const bool hasR = (c0 < WW - 4);
    const int  colL = hasL ? c0 - 2 : c0;   // aligned float2, clamped
    const int  colR = hasR ? c0 + 4 : c0;

#define LOADCVT(P_, base, off) do {                                          \
    const float4 _q = *reinterpret_cast<const float4*>((base) + (off) + c0); \
    const float2 _l = *reinterpret_cast<const float2*>((base) + (off) + colL); \
    const float2 _r = *reinterpret_cast<const float2*>((base) + (off) + colR); \
    const float _eL = hasL ? _l.y : 0.0f;                                    \
    const float _eR = hasR ? _r.x : 0.0f;                                    \
    P_[0] = pkrtz(_eL, _q.x);                                                \
    P_[1] = pkrtz(_q.x, _q.y);                                               \
    P_[2] = pkrtz(_q.y, _q.z);                                               \
    P_[3] = pkrtz(_q.z, _q.w);                                               \
    P_[4] = pkrtz(_q.w, _eR);                                                \
} while (0)

#define LOADWIN(W_, r) do {                                                  \
    const int _o = (r) * WW;                                                 \
    LOADCVT(W_.d, dptr, _o); LOADCVT(W_.m, mptr, _o);                        \
    LOADCVT(W_.x, xptr, _o); LOADCVT(W_.y, yptr, _o);                        \
    LOADCVT(W_.z, zptr, _o);                                                 \
} while (0)

// One tap: source pack pi of window S_ vs one pixel-pair's centers.
#define TAP(S_, pi, cD, cX, cY, cZ, WSC, A_) do {                            \
    const h2 _wd = wpoly(S_.d[pi] - (cD));                                   \
    const h2 _w0 = wpoly(S_.x[pi] - (cX));                                   \
    const h2 _w1 = wpoly(S_.y[pi] - (cY));                                   \
    const h2 _w2 = wpoly(S_.z[pi] - (cZ));                                   \
    const h2 _wc = _w0 + _w1 + _w2;                                          \
    const h2 _t  = (_wd * _wc) * (H2c(WSC) * S_.m[pi]);                      \
    A_.swd += _wd; A_.swc += _wc; A_.st += _t;                               \
    A_.s0 += _t * S_.x[pi]; A_.s1 += _t * S_.y[pi]; A_.s2 += _t * S_.z[pi];  \
} while (0)

// All 6 taps (2 pixel-pairs x 3 cols) of source row S_ against one output
// row's centers. Pair 0 (cols c0,c1) uses packs 0,1,2; pair 1 uses 2,3,4.
#define ROWPASS(S_, cd0,cx0,cy0,cz0, cd1,cx1,cy1,cz1, A0_, A1_, WSM, WSS) do { \
    TAP(S_, 0, cd0, cx0, cy0, cz0, WSS, A0_);                                \
    TAP(S_, 1, cd0, cx0, cy0, cz0, WSM, A0_);                                \
    TAP(S_, 2, cd0, cx0, cy0, cz0, WSS, A0_);                                \
    TAP(S_, 2, cd1, cx1, cy1, cz1, WSS, A1_);                                \
    TAP(S_, 3, cd1, cx1, cy1, cz1, WSM, A1_);                                \
    TAP(S_, 4, cd1, cx1, cy1, cz1, WSS, A1_);                                \
} while (0)

    RW A, B;
    LOADWIN(A, rA);
    LOADWIN(B, rA + 1);

    // Center copies (let A/B windows die before side-row passes reuse regs).
    const h2 cad0 = A.d[1], cad1 = A.d[3];
    const h2 cax0 = A.x[1], cax1 = A.x[3];
    const h2 cay0 = A.y[1], cay1 = A.y[3];
    const h2 caz0 = A.z[1], caz1 = A.z[3];
    const h2 cbd0 = B.d[1], cbd1 = B.d[3];
    const h2 cbx0 = B.x[1], cbx1 = B.x[3];
    const h2 cby0 = B.y[1], cby1 = B.y[3];
    const h2 cbz0 = B.z[1], cbz1 = B.z[3];

    Acc aa0{}, aa1{}, ab0{}, ab1{};   // zero-init

    ROWPASS(A, cad0,cax0,cay0,caz0, cad1,cax1,cay1,caz1, aa0, aa1, WS0f, WS1f);
    ROWPASS(B, cbd0,cbx0,cby0,cbz0, cbd1,cbx1,cby1,cbz1, ab0, ab1, WS0f, WS1f);
    ROWPASS(B, cad0,cax0,cay0,caz0, cad1,cax1,cay1,caz1, aa0, aa1, WS1f, WS2f);
    ROWPASS(A, cbd0,cbx0,cby0,cbz0, cbd1,cbx1,cby1,cbz1, ab0, ab1, WS1f, WS2f);

    const bool hasUp = (hp > 0);      // wave-uniform
    const bool hasDn = (hp < 255);    // wave-uniform

    if (hasUp) {
        RW T;
        LOADWIN(T, rA - 1);
        ROWPASS(T, cad0,cax0,cay0,caz0, cad1,cax1,cay1,caz1, aa0, aa1, WS1f, WS2f);
    }
    if (hasDn) {
        RW T;
        LOADWIN(T, rA + 2);
        ROWPASS(T, cbd0,cbx0,cby0,cbz0, cbd1,cbx1,cby1,cbz1, ab0, ab1, WS1f, WS2f);
    }
    // (top/bottom skipped rows only affect the 9e-7 guard term; established)

    // fp32 epilogue: out = S / (St + 9e-7*Swd*Swc)
#define EPI(A_, o0, o1, o2, i0, i1) do {                                     \
    {                                                                        \
        const float st  = (float)A_.st[0];                                   \
        const float g   = st + 9e-7f * (float)A_.swd[0] * (float)A_.swc[0];  \
        const float inv = __builtin_amdgcn_rcpf(g);                          \
        o0[i0] = (float)A_.s0[0] * inv;                                      \
        o1[i0] = (float)A_.s1[0] * inv;                                      \
        o2[i0] = (float)A_.s2[0] * inv;                                      \
    }                                                                        \
    {                                                                        \
        const float st  = (float)A_.st[1];                                   \
        const float g   = st + 9e-7f * (float)A_.swd[1] * (float)A_.swc[1];  \
        const float inv = __builtin_amdgcn_rcpf(g);                          \
        o0[i1] = (float)A_.s0[1] * inv;                                      \
        o1[i1] = (float)A_.s1[1] * inv;                                      \
        o2[i1] = (float)A_.s2[1] * inv;                                      \
    }                                                                        \
} while (0)

    float ra0[4], ra1[4], ra2[4], rb0[4], rb1[4], rb2[4];
    EPI(aa0, ra0, ra1, ra2, 0, 1);
    EPI(aa1, ra0, ra1, ra2, 2, 3);
    EPI(ab0, rb0, rb1, rb2, 0, 1);
    EPI(ab1, rb0, rb1, rb2, 2, 3);

    float* po = out + (size_t)n * 3 * HW + rA * WW + c0;
    *reinterpret_cast<float4*>(po)               = make_float4(ra0[0], ra0[1], ra0[2], ra0[3]);
    *reinterpret_cast<float4*>(po + HW)          = make_float4(ra1[0], ra1[1], ra1[2], ra1[3]);
    *reinterpret_cast<float4*>(po + 2 * HW)      = make_float4(ra2[0], ra2[1], ra2[2], ra2[3]);
    *reinterpret_cast<float4*>(po + WW)          = make_float4(rb0[0], rb0[1], rb0[2], rb0[3]);
    *reinterpret_cast<float4*>(po + WW + HW)     = make_float4(rb1[0], rb1[1], rb1[2], rb1[3]);
    *reinterpret_cast<float4*>(po + WW + 2 * HW) = make_float4(rb2[0], rb2[1], rb2[2], rb2[3]);
}

extern "C" void kernel_launch(void* const* d_in, const int* in_sizes, int n_in,
                              void* d_out, int out_size, void* d_ws, size_t ws_size,
                              hipStream_t stream) {
    const float* depth = (const float*)d_in[0];
    const float* color = (const float*)d_in[1];
    const float* mask  = (const float*)d_in[2];
    float* out = (float*)d_out;

    // 8 images * 256 row-pairs * 2 halves = 4096 waves; 4 waves/block
    bilateral_v11<<<1024, 256, 0, stream>>>(depth, color, mask, out);
}